// Round 1
// baseline (451.650 us; speedup 1.0000x reference)
//
#include <hip/hip_runtime.h>
#include <hip/hip_bf16.h>

typedef unsigned short u16;
typedef short bf16x8 __attribute__((ext_vector_type(8)));
typedef float f32x4 __attribute__((ext_vector_type(4)));

#define N_    16
#define CIN   512
#define COUT  512
#define WD    512
#define P_    4096   // 64*64 spatial

// ws layout (bytes)
#define OFF_S   0u
#define OFF_D   32768u
#define OFF_Z   65536u          // 1 KB zero page
#define OFF_WBT 131072u         // 9*512*512*2 = 4718592 B
#define OFF_XB  8388608u        // 16*4096*512*2 = 67108864 B
#define WS_NEED (OFF_XB + 67108864u)

__device__ __forceinline__ u16 f2bf(float f) {
  union { float f; unsigned u; } a; a.f = f;
  unsigned r = a.u + 0x7fffu + ((a.u >> 16) & 1u);   // RNE
  return (u16)(r >> 16);
}

__device__ __forceinline__ void gl_lds16(const u16* g, u16* l) {
  __builtin_amdgcn_global_load_lds(
      (const __attribute__((address_space(1))) void*)g,
      (__attribute__((address_space(3))) void*)l, 16, 0, 0);
}

// ---------- zero page ----------
__global__ void k_zero(float* z) { z[threadIdx.x] = 0.f; }

// ---------- s = w @ affine_w^T + affine_b ----------
__global__ __launch_bounds__(256) void k_affine(const float* __restrict__ w,
                                                const float* __restrict__ aw,
                                                const float* __restrict__ ab,
                                                float* __restrict__ s) {
  int idx = blockIdx.x * 256 + threadIdx.x;       // 16*512
  int n = idx >> 9, c = idx & 511;
  const float4* wr = (const float4*)(w + (size_t)n * WD);
  const float4* ar = (const float4*)(aw + (size_t)c * WD);
  float acc = 0.f;
#pragma unroll 4
  for (int k = 0; k < WD / 4; ++k) {
    float4 a = wr[k], b = ar[k];
    acc += a.x * b.x + a.y * b.y + a.z * b.z + a.w * b.w;
  }
  s[idx] = acc + ab[c];
}

// ---------- d = rsqrt(sum_i s^2 * w2 + 1e-8) ----------
__global__ __launch_bounds__(256) void k_demod(const float* __restrict__ s,
                                               const float* __restrict__ cw,
                                               float* __restrict__ d) {
  __shared__ float w2[CIN];
  int o = blockIdx.x;
  const float* wr = cw + (size_t)o * CIN * 9;
  for (int i = threadIdx.x; i < CIN; i += 256) {
    float acc = 0.f;
#pragma unroll
    for (int t = 0; t < 9; ++t) { float v = wr[i * 9 + t]; acc += v * v; }
    w2[i] = acc;
  }
  __syncthreads();
  int wave = threadIdx.x >> 6, lane = threadIdx.x & 63;
  for (int nn = wave; nn < N_; nn += 4) {
    float acc = 0.f;
    for (int i = lane; i < CIN; i += 64) {
      float sv = s[nn * CIN + i];
      acc += sv * sv * w2[i];
    }
#pragma unroll
    for (int off = 32; off > 0; off >>= 1) acc += __shfl_down(acc, off);
    if (lane == 0) {
      float a = acc + 1e-8f;
      float r = rsqrtf(a);
      r = r * (1.5f - 0.5f * a * r * r);   // Newton refine
      d[nn * COUT + o] = r;
    }
  }
}

// ---------- weights -> bf16, layout [tap][o][i] ----------
__global__ __launch_bounds__(256) void k_wprep(const float* __restrict__ cw,
                                               u16* __restrict__ wbt) {
  int idx = blockIdx.x * 256 + threadIdx.x;
  if (idx >= COUT * CIN * 9) return;
  int t = idx % 9; int oi = idx / 9; int i = oi & 511; int o = oi >> 9;
  wbt[((size_t)t * COUT + o) * CIN + i] = f2bf(cw[idx]);
}

// ---------- x * s -> bf16 NHWC  xb[n][p][c] ----------
__global__ __launch_bounds__(256) void k_xmod(const float* __restrict__ x,
                                              const float* __restrict__ s,
                                              u16* __restrict__ xb) {
  __shared__ float tile[64][65];
  int b = blockIdx.x;                 // 16 * 8 * 64
  int pt = b & 63; int ct = (b >> 6) & 7; int n = b >> 9;
  int c0 = ct * 64, p0 = pt * 64;
  const float* xp = x + ((size_t)n * CIN + c0) * P_ + p0;
  int t = threadIdx.x;
#pragma unroll
  for (int pass = 0; pass < 4; ++pass) {
    int r = pass * 16 + (t >> 4);
    int col4 = (t & 15);
    float4 v = *(const float4*)(xp + (size_t)r * P_ + col4 * 4);
    float sc = s[n * CIN + c0 + r];
    tile[r][col4 * 4 + 0] = v.x * sc;
    tile[r][col4 * 4 + 1] = v.y * sc;
    tile[r][col4 * 4 + 2] = v.z * sc;
    tile[r][col4 * 4 + 3] = v.w * sc;
  }
  __syncthreads();
  int p = t >> 2, cq = (t & 3) * 16;
  union { u16 us[16]; uint4 q[2]; } pk;
#pragma unroll
  for (int j = 0; j < 16; ++j) pk.us[j] = f2bf(tile[cq + j][p]);
  uint4* dst = (uint4*)(xb + ((size_t)n * P_ + p0 + p) * CIN + c0 + cq);
  dst[0] = pk.q[0];
  dst[1] = pk.q[1];
}

// ---------- main conv: implicit GEMM, 128x128 tile, BK=32 ----------
__global__ __launch_bounds__(256) void k_conv(const u16* __restrict__ xb,
                                              const u16* __restrict__ wbt,
                                              const u16* __restrict__ zpage,
                                              const float* __restrict__ dmod,
                                              const float* __restrict__ cbias,
                                              const float* __restrict__ noise,
                                              const float* __restrict__ nstr,
                                              float* __restrict__ out) {
  __shared__ u16 smA[128 * 32];
  __shared__ u16 smB[128 * 32];
  int bid = blockIdx.x;                 // 2048 = 16n * 4ob * 32pb
  int n = bid >> 7;
  int r7 = bid & 127;
  int ob = (r7 & 3) * 128;
  int pbi = r7 >> 2;
  int pb = pbi * 128;
  int h0 = pbi * 2;

  int tid = threadIdx.x;
  int wv = tid >> 6, l = tid & 63;
  int sub = l >> 2, quad = l & 3;
  int wr = wv >> 1, wc = wv & 1;
  int lrow = l & 15, kgrp = l >> 4;

  int rA0 = wv * 16 + sub, rA1 = rA0 + 64;   // staging rows (A and B share scheme)
  int hj0 = h0 + (rA0 >> 6), wj0 = rA0 & 63;
  int hj1 = h0 + (rA1 >> 6), wj1 = rA1 & 63;
  const u16* xbn = xb + (size_t)n * P_ * CIN;

  f32x4 acc[4][4];
  f32x4 zero = {0.f, 0.f, 0.f, 0.f};
#pragma unroll
  for (int i = 0; i < 4; ++i)
#pragma unroll
    for (int j = 0; j < 4; ++j) acc[i][j] = zero;

  u16* dA0 = &smA[(size_t)wv * 512];
  u16* dA1 = &smA[(size_t)(wv + 4) * 512];
  u16* dB0 = &smB[(size_t)wv * 512];
  u16* dB1 = &smB[(size_t)(wv + 4) * 512];

  for (int tap = 0; tap < 9; ++tap) {
    int dh = tap / 3 - 1, dw = tap % 3 - 1;
    int hh0 = hj0 + dh, ww0 = wj0 + dw;
    int hh1 = hj1 + dh, ww1 = wj1 + dw;
    const u16* b0 = ((unsigned)hh0 < 64u && (unsigned)ww0 < 64u)
                        ? xbn + ((size_t)(hh0 * 64 + ww0)) * CIN + quad * 8
                        : zpage + quad * 8;
    const u16* b1 = ((unsigned)hh1 < 64u && (unsigned)ww1 < 64u)
                        ? xbn + ((size_t)(hh1 * 64 + ww1)) * CIN + quad * 8
                        : zpage + quad * 8;
    const u16* a0 = wbt + ((size_t)tap * COUT + ob + rA0) * CIN + quad * 8;
    const u16* a1 = wbt + ((size_t)tap * COUT + ob + rA1) * CIN + quad * 8;
    for (int cb = 0; cb < 16; ++cb) {
      int ko = cb * 32;
      gl_lds16(a0 + ko, dA0);
      gl_lds16(a1 + ko, dA1);
      gl_lds16(b0 + ko, dB0);
      gl_lds16(b1 + ko, dB1);
      __syncthreads();
      bf16x8 af[4], bfr[4];
#pragma unroll
      for (int mi = 0; mi < 4; ++mi)
        af[mi] = *(const bf16x8*)&smA[(wr * 64 + mi * 16 + lrow) * 32 + kgrp * 8];
#pragma unroll
      for (int ni = 0; ni < 4; ++ni)
        bfr[ni] = *(const bf16x8*)&smB[(wc * 64 + ni * 16 + lrow) * 32 + kgrp * 8];
#pragma unroll
      for (int mi = 0; mi < 4; ++mi)
#pragma unroll
        for (int ni = 0; ni < 4; ++ni)
          acc[mi][ni] = __builtin_amdgcn_mfma_f32_16x16x32_bf16(
              af[mi], bfr[ni], acc[mi][ni], 0, 0, 0);
      __syncthreads();
    }
  }

  // epilogue: demod scale + bias + noise + LeakyReLU(0.2)
  float ns = nstr[0];
  const float* noise_n = noise + (size_t)n * P_;
  float nz[4];
#pragma unroll
  for (int ni = 0; ni < 4; ++ni)
    nz[ni] = noise_n[pb + wc * 64 + ni * 16 + lrow] * ns;
#pragma unroll
  for (int mi = 0; mi < 4; ++mi) {
    int o0 = ob + wr * 64 + mi * 16 + kgrp * 4;
#pragma unroll
    for (int r = 0; r < 4; ++r) {
      int o = o0 + r;
      float dv = dmod[n * COUT + o];
      float bv = cbias[o];
      float* orow = out + ((size_t)(n * COUT + o)) * P_ + pb + wc * 64;
#pragma unroll
      for (int ni = 0; ni < 4; ++ni) {
        float v = acc[mi][ni][r] * dv + bv + nz[ni];
        orow[ni * 16 + lrow] = v >= 0.f ? v : 0.2f * v;
      }
    }
  }
}

// ---------- fallback (small ws): direct conv ----------
__global__ __launch_bounds__(64) void k_conv_naive(const float* __restrict__ x,
                                                   const float* __restrict__ cw,
                                                   const float* __restrict__ cbias,
                                                   const float* __restrict__ noise,
                                                   const float* __restrict__ nstr,
                                                   const float* __restrict__ s,
                                                   const float* __restrict__ d,
                                                   float* __restrict__ out) {
  int bid = blockIdx.x;                 // 16*512*64 = (n,o,h)
  int h = bid & 63; int o = (bid >> 6) & 511; int n = bid >> 15;
  int wcol = threadIdx.x;
  float acc = 0.f;
  for (int i = 0; i < CIN; ++i) {
    float sv = s[n * CIN + i];
    const float* xrow = x + ((size_t)(n * CIN + i)) * P_;
    const float* wrp = cw + ((size_t)o * CIN + i) * 9;
#pragma unroll
    for (int t = 0; t < 9; ++t) {
      int hh = h + t / 3 - 1, ww = wcol + t % 3 - 1;
      float xv = ((unsigned)hh < 64u && (unsigned)ww < 64u) ? xrow[hh * 64 + ww] : 0.f;
      acc += xv * sv * wrp[t];
    }
  }
  float v = acc * d[n * COUT + o] + cbias[o] + noise[(size_t)n * P_ + h * 64 + wcol] * nstr[0];
  out[((size_t)(n * COUT + o)) * P_ + h * 64 + wcol] = v >= 0.f ? v : 0.2f * v;
}

extern "C" void kernel_launch(void* const* d_in, const int* in_sizes, int n_in,
                              void* d_out, int out_size, void* d_ws, size_t ws_size,
                              hipStream_t stream) {
  const float* x    = (const float*)d_in[0];
  const float* w    = (const float*)d_in[1];
  const float* noise= (const float*)d_in[2];
  const float* aw   = (const float*)d_in[3];
  const float* ab   = (const float*)d_in[4];
  const float* nstr = (const float*)d_in[5];
  const float* cw   = (const float*)d_in[6];
  const float* cb   = (const float*)d_in[7];
  float* out = (float*)d_out;
  char* ws = (char*)d_ws;
  float* s = (float*)(ws + OFF_S);
  float* d = (float*)(ws + OFF_D);

  k_affine<<<(N_ * COUT) / 256, 256, 0, stream>>>(w, aw, ab, s);
  k_demod<<<COUT, 256, 0, stream>>>(s, cw, d);

  if (ws_size >= WS_NEED) {
    u16* zp  = (u16*)(ws + OFF_Z);
    u16* wbt = (u16*)(ws + OFF_WBT);
    u16* xb  = (u16*)(ws + OFF_XB);
    k_zero<<<1, 256, 0, stream>>>((float*)zp);
    k_wprep<<<(COUT * CIN * 9 + 255) / 256, 256, 0, stream>>>(cw, wbt);
    k_xmod<<<N_ * 8 * 64, 256, 0, stream>>>(x, s, xb);
    k_conv<<<N_ * 4 * 32, 256, 0, stream>>>(xb, wbt, zp, d, cb, noise, nstr, out);
  } else {
    k_conv_naive<<<N_ * COUT * 64, 64, 0, stream>>>(x, cw, cb, noise, nstr, s, d, out);
  }
}

// Round 2
// 346.299 us; speedup vs baseline: 1.3042x; 1.3042x over previous
//
#include <hip/hip_runtime.h>
#include <hip/hip_bf16.h>

typedef unsigned short u16;
typedef short bf16x8 __attribute__((ext_vector_type(8)));
typedef float f32x4 __attribute__((ext_vector_type(4)));

#define N_    16
#define CIN   512
#define COUT  512
#define WD    512
#define P_    4096   // 64*64 spatial

// ws layout (bytes)
#define OFF_S   0u
#define OFF_D   32768u
#define OFF_Z   65536u          // 1 KB zero page
#define OFF_WBT 131072u         // 9*512*512*2 = 4718592 B
#define OFF_XB  8388608u        // 16*4096*512*2 = 67108864 B
#define WS_NEED (OFF_XB + 67108864u)

__device__ __forceinline__ u16 f2bf(float f) {
  union { float f; unsigned u; } a; a.f = f;
  unsigned r = a.u + 0x7fffu + ((a.u >> 16) & 1u);   // RNE
  return (u16)(r >> 16);
}

__device__ __forceinline__ void gl_lds16(const u16* g, u16* l) {
  __builtin_amdgcn_global_load_lds(
      (const __attribute__((address_space(1))) void*)g,
      (__attribute__((address_space(3))) void*)l, 16, 0, 0);
}

// ---------- zero page ----------
__global__ void k_zero(float* z) { z[threadIdx.x] = 0.f; }

// ---------- s = w @ affine_w^T + affine_b ----------
__global__ __launch_bounds__(256) void k_affine(const float* __restrict__ w,
                                                const float* __restrict__ aw,
                                                const float* __restrict__ ab,
                                                float* __restrict__ s) {
  int idx = blockIdx.x * 256 + threadIdx.x;       // 16*512
  int n = idx >> 9, c = idx & 511;
  const float4* wr = (const float4*)(w + (size_t)n * WD);
  const float4* ar = (const float4*)(aw + (size_t)c * WD);
  float acc = 0.f;
#pragma unroll 4
  for (int k = 0; k < WD / 4; ++k) {
    float4 a = wr[k], b = ar[k];
    acc += a.x * b.x + a.y * b.y + a.z * b.z + a.w * b.w;
  }
  s[idx] = acc + ab[c];
}

// ---------- d = rsqrt(sum_i s^2 * w2 + 1e-8) ----------
__global__ __launch_bounds__(256) void k_demod(const float* __restrict__ s,
                                               const float* __restrict__ cw,
                                               float* __restrict__ d) {
  __shared__ float w2[CIN];
  int o = blockIdx.x;
  const float* wr = cw + (size_t)o * CIN * 9;
  for (int i = threadIdx.x; i < CIN; i += 256) {
    float acc = 0.f;
#pragma unroll
    for (int t = 0; t < 9; ++t) { float v = wr[i * 9 + t]; acc += v * v; }
    w2[i] = acc;
  }
  __syncthreads();
  int wave = threadIdx.x >> 6, lane = threadIdx.x & 63;
  for (int nn = wave; nn < N_; nn += 4) {
    float acc = 0.f;
    for (int i = lane; i < CIN; i += 64) {
      float sv = s[nn * CIN + i];
      acc += sv * sv * w2[i];
    }
#pragma unroll
    for (int off = 32; off > 0; off >>= 1) acc += __shfl_down(acc, off);
    if (lane == 0) {
      float a = acc + 1e-8f;
      float r = rsqrtf(a);
      r = r * (1.5f - 0.5f * a * r * r);   // Newton refine
      d[nn * COUT + o] = r;
    }
  }
}

// ---------- weights -> bf16, layout [tap][o][i] ----------
__global__ __launch_bounds__(256) void k_wprep(const float* __restrict__ cw,
                                               u16* __restrict__ wbt) {
  int idx = blockIdx.x * 256 + threadIdx.x;
  if (idx >= COUT * CIN * 9) return;
  int t = idx % 9; int oi = idx / 9; int i = oi & 511; int o = oi >> 9;
  wbt[((size_t)t * COUT + o) * CIN + i] = f2bf(cw[idx]);
}

// ---------- x * s -> bf16 NHWC  xb[n][p][c] ----------
__global__ __launch_bounds__(256) void k_xmod(const float* __restrict__ x,
                                              const float* __restrict__ s,
                                              u16* __restrict__ xb) {
  __shared__ float tile[64][65];
  int b = blockIdx.x;                 // 16 * 8 * 64
  int pt = b & 63; int ct = (b >> 6) & 7; int n = b >> 9;
  int c0 = ct * 64, p0 = pt * 64;
  const float* xp = x + ((size_t)n * CIN + c0) * P_ + p0;
  int t = threadIdx.x;
#pragma unroll
  for (int pass = 0; pass < 4; ++pass) {
    int r = pass * 16 + (t >> 4);
    int col4 = (t & 15);
    float4 v = *(const float4*)(xp + (size_t)r * P_ + col4 * 4);
    float sc = s[n * CIN + c0 + r];
    tile[r][col4 * 4 + 0] = v.x * sc;
    tile[r][col4 * 4 + 1] = v.y * sc;
    tile[r][col4 * 4 + 2] = v.z * sc;
    tile[r][col4 * 4 + 3] = v.w * sc;
  }
  __syncthreads();
  int p = t >> 2, cq = (t & 3) * 16;
  union { u16 us[16]; uint4 q[2]; } pk;
#pragma unroll
  for (int j = 0; j < 16; ++j) pk.us[j] = f2bf(tile[cq + j][p]);
  uint4* dst = (uint4*)(xb + ((size_t)n * P_ + p0 + p) * CIN + c0 + cq);
  dst[0] = pk.q[0];
  dst[1] = pk.q[1];
}

// ---------- main conv: implicit GEMM, 256x256 tile, BK=32, ring-4 LDS ----------
// 512 threads = 8 waves (2 wr x 4 wc); per-wave output 128x64.
// Per tile: gate {vmcnt(4); s_barrier}; phase A (qm=0): 8 A-frag + 4 B-frag
// ds_read_b128, issue A-stage for tile t+2, 16 MFMA; phase B (qm=1): 4 A-frag
// reads, issue B-stage for t+2, 16 MFMA. One barrier / 32 MFMA; vmcnt never
// drains to 0 in the main loop (ring-4: stage target dead for 2 tiles).
__global__ __launch_bounds__(512, 1) void k_conv(const u16* __restrict__ xb,
                                                 const u16* __restrict__ wbt,
                                                 const u16* __restrict__ zp,
                                                 const float* __restrict__ dmod,
                                                 const float* __restrict__ cbias,
                                                 const float* __restrict__ noise,
                                                 const float* __restrict__ nstr,
                                                 float* __restrict__ out) {
  __shared__ u16 smA[4][8192];   // [buf][256 rows x 32 ch] 16 KB each
  __shared__ u16 smB[4][8192];

  // bijective XCD swizzle: nwg=512, 512%8==0 -> XCD x gets n in {2x,2x+1}
  int bid = blockIdx.x;
  int wg = (bid & 7) * 64 + (bid >> 3);
  int n = wg >> 5;
  int rem = wg & 31;
  int ob = rem >> 4;            // 0..1   (out-ch block of 256)
  int pb = rem & 15;            // 0..15  (spatial block of 256 = 4 rows)

  int tid = threadIdx.x;
  int wv = tid >> 6, l = tid & 63;
  int wr = wv >> 2, wc = wv & 3;
  int lrow = l & 15, kgrp = l >> 4;
  int prs = kgrp ^ ((lrow >> 1) & 3);          // read phys slot (swizzle)

  // staging constants
  int srow = tid >> 2;                          // 0..127 row within group
  int lslot = (tid & 3) ^ ((tid >> 3) & 3);     // logical k-slot staged
  const u16* xbn = xb + (size_t)n * P_ * CIN;
  int hg[2], wgp[2];
#pragma unroll
  for (int g = 0; g < 2; ++g) {
    int ploc = g * 128 + srow;
    hg[g] = pb * 4 + (ploc >> 6);
    wgp[g] = ploc & 63;
  }
  const u16* srcA_base[2];
#pragma unroll
  for (int g = 0; g < 2; ++g)
    srcA_base[g] = wbt + (size_t)(ob * 256 + g * 128 + srow) * CIN + lslot * 8;

  auto stage_A = [&](int tt) {
    int b = tt & 3;
    int tapn = tt >> 4, cbn = tt & 15;
#pragma unroll
    for (int g = 0; g < 2; ++g) {
      const u16* src = srcA_base[g] + (size_t)tapn * (COUT * CIN) + cbn * 32;
      gl_lds16(src, &smA[b][g * 4096 + wv * 512]);
    }
  };
  auto stage_B = [&](int tt) {
    int b = tt & 3;
    int tapn = tt >> 4, cbn = tt & 15;
    int q = (tapn * 11) >> 5;            // tapn/3 for 0..8
    int dh = q - 1, dw = tapn - q * 3 - 1;
#pragma unroll
    for (int g = 0; g < 2; ++g) {
      int hh = hg[g] + dh, ww = wgp[g] + dw;
      bool val = ((unsigned)hh < 64u) && ((unsigned)ww < 64u);
      const u16* src = val ? (xbn + ((size_t)((hh << 6) + ww)) * CIN + cbn * 32 + lslot * 8)
                           : (zp + lslot * 8);
      gl_lds16(src, &smB[b][g * 4096 + wv * 512]);
    }
  };

  f32x4 acc0[4][4], acc1[4][4];
  f32x4 zero = {0.f, 0.f, 0.f, 0.f};
#pragma unroll
  for (int i = 0; i < 4; ++i)
#pragma unroll
    for (int j = 0; j < 4; ++j) { acc0[i][j] = zero; acc1[i][j] = zero; }

  // prologue: stage tiles 0 and 1 (8 loads in flight)
  stage_A(0); stage_B(0);
  stage_A(1); stage_B(1);

  for (int t = 0; t < 144; ++t) {      // 9 taps * 16 cb
    int b = t & 3;
    if (t < 143) asm volatile("s_waitcnt vmcnt(4)" ::: "memory");
    else         asm volatile("s_waitcnt vmcnt(0)" ::: "memory");
    __builtin_amdgcn_s_barrier();
    __builtin_amdgcn_sched_barrier(0);

    const u16* A = smA[b];
    const u16* B = smB[b];
    bf16x8 Af[4], Bf[4];
#pragma unroll
    for (int ni = 0; ni < 4; ++ni)
      Bf[ni] = *(const bf16x8*)&B[(wc * 64 + ni * 16 + lrow) * 32 + prs * 8];
#pragma unroll
    for (int mi = 0; mi < 4; ++mi)
      Af[mi] = *(const bf16x8*)&A[(wr * 128 + mi * 16 + lrow) * 32 + prs * 8];
    if (t < 142) stage_A(t + 2);
    __builtin_amdgcn_s_setprio(1);
#pragma unroll
    for (int mi = 0; mi < 4; ++mi)
#pragma unroll
      for (int ni = 0; ni < 4; ++ni)
        acc0[mi][ni] = __builtin_amdgcn_mfma_f32_16x16x32_bf16(
            Af[mi], Bf[ni], acc0[mi][ni], 0, 0, 0);
    __builtin_amdgcn_s_setprio(0);

#pragma unroll
    for (int mi = 0; mi < 4; ++mi)
      Af[mi] = *(const bf16x8*)&A[(wr * 128 + 64 + mi * 16 + lrow) * 32 + prs * 8];
    if (t < 142) stage_B(t + 2);
    __builtin_amdgcn_s_setprio(1);
#pragma unroll
    for (int mi = 0; mi < 4; ++mi)
#pragma unroll
      for (int ni = 0; ni < 4; ++ni)
        acc1[mi][ni] = __builtin_amdgcn_mfma_f32_16x16x32_bf16(
            Af[mi], Bf[ni], acc1[mi][ni], 0, 0, 0);
    __builtin_amdgcn_s_setprio(0);
  }

  // epilogue: demod scale + bias + noise + LeakyReLU(0.2)
  float ns = nstr[0];
  const float* noise_n = noise + (size_t)n * P_;
  float nz[4];
#pragma unroll
  for (int ni = 0; ni < 4; ++ni)
    nz[ni] = noise_n[pb * 256 + wc * 64 + ni * 16 + lrow] * ns;

  auto epi = [&](f32x4 (&A_)[4][4], int qm) {
#pragma unroll
    for (int mi = 0; mi < 4; ++mi) {
      int o0 = ob * 256 + wr * 128 + qm * 64 + mi * 16 + kgrp * 4;
#pragma unroll
      for (int r = 0; r < 4; ++r) {
        int o = o0 + r;
        float dv = dmod[n * COUT + o];
        float bv = cbias[o];
        float* orow = out + ((size_t)(n * COUT + o)) * P_ + pb * 256 + wc * 64;
#pragma unroll
        for (int ni = 0; ni < 4; ++ni) {
          float v = A_[mi][ni][r] * dv + bv + nz[ni];
          orow[ni * 16 + lrow] = v >= 0.f ? v : 0.2f * v;
        }
      }
    }
  };
  epi(acc0, 0);
  epi(acc1, 1);
}

// ---------- fallback (small ws): direct conv ----------
__global__ __launch_bounds__(64) void k_conv_naive(const float* __restrict__ x,
                                                   const float* __restrict__ cw,
                                                   const float* __restrict__ cbias,
                                                   const float* __restrict__ noise,
                                                   const float* __restrict__ nstr,
                                                   const float* __restrict__ s,
                                                   const float* __restrict__ d,
                                                   float* __restrict__ out) {
  int bid = blockIdx.x;                 // 16*512*64 = (n,o,h)
  int h = bid & 63; int o = (bid >> 6) & 511; int n = bid >> 15;
  int wcol = threadIdx.x;
  float acc = 0.f;
  for (int i = 0; i < CIN; ++i) {
    float sv = s[n * CIN + i];
    const float* xrow = x + ((size_t)(n * CIN + i)) * P_;
    const float* wrp = cw + ((size_t)o * CIN + i) * 9;
#pragma unroll
    for (int t = 0; t < 9; ++t) {
      int hh = h + t / 3 - 1, ww = wcol + t % 3 - 1;
      float xv = ((unsigned)hh < 64u && (unsigned)ww < 64u) ? xrow[hh * 64 + ww] : 0.f;
      acc += xv * sv * wrp[t];
    }
  }
  float v = acc * d[n * COUT + o] + cbias[o] + noise[(size_t)n * P_ + h * 64 + wcol] * nstr[0];
  out[((size_t)(n * COUT + o)) * P_ + h * 64 + wcol] = v >= 0.f ? v : 0.2f * v;
}

extern "C" void kernel_launch(void* const* d_in, const int* in_sizes, int n_in,
                              void* d_out, int out_size, void* d_ws, size_t ws_size,
                              hipStream_t stream) {
  const float* x    = (const float*)d_in[0];
  const float* w    = (const float*)d_in[1];
  const float* noise= (const float*)d_in[2];
  const float* aw   = (const float*)d_in[3];
  const float* ab   = (const float*)d_in[4];
  const float* nstr = (const float*)d_in[5];
  const float* cw   = (const float*)d_in[6];
  const float* cb   = (const float*)d_in[7];
  float* out = (float*)d_out;
  char* ws = (char*)d_ws;
  float* s = (float*)(ws + OFF_S);
  float* d = (float*)(ws + OFF_D);

  k_affine<<<(N_ * COUT) / 256, 256, 0, stream>>>(w, aw, ab, s);
  k_demod<<<COUT, 256, 0, stream>>>(s, cw, d);

  if (ws_size >= WS_NEED) {
    u16* zp  = (u16*)(ws + OFF_Z);
    u16* wbt = (u16*)(ws + OFF_WBT);
    u16* xbb = (u16*)(ws + OFF_XB);
    k_zero<<<1, 256, 0, stream>>>((float*)zp);
    k_wprep<<<(COUT * CIN * 9 + 255) / 256, 256, 0, stream>>>(cw, wbt);
    k_xmod<<<N_ * 8 * 64, 256, 0, stream>>>(x, s, xbb);
    k_conv<<<512, 512, 0, stream>>>(xbb, wbt, zp, d, cb, noise, nstr, out);
  } else {
    k_conv_naive<<<N_ * COUT * 64, 64, 0, stream>>>(x, cw, cb, noise, nstr, s, d, out);
  }
}

// Round 3
// 342.901 us; speedup vs baseline: 1.3171x; 1.0099x over previous
//
#include <hip/hip_runtime.h>
#include <hip/hip_bf16.h>

typedef unsigned short u16;
typedef short bf16x8 __attribute__((ext_vector_type(8)));
typedef float f32x4 __attribute__((ext_vector_type(4)));

#define N_    16
#define CIN   512
#define COUT  512
#define WD    512
#define P_    4096   // 64*64 spatial
#define CC    (COUT * CIN)

// ws layout (bytes)
#define OFF_S   0u
#define OFF_D   32768u
#define OFF_Z   65536u          // 1 KB zero page
#define OFF_WBT 131072u         // 9*512*512*2 = 4718592 B
#define OFF_XB  8388608u        // 16*4096*512*2 = 67108864 B
#define WS_NEED (OFF_XB + 67108864u)

__device__ __forceinline__ u16 f2bf(float f) {
  union { float f; unsigned u; } a; a.f = f;
  unsigned r = a.u + 0x7fffu + ((a.u >> 16) & 1u);   // RNE
  return (u16)(r >> 16);
}

__device__ __forceinline__ void gl_lds16(const u16* g, u16* l) {
  __builtin_amdgcn_global_load_lds(
      (const __attribute__((address_space(1))) void*)g,
      (__attribute__((address_space(3))) void*)l, 16, 0, 0);
}

// ---------- zero page ----------
__global__ void k_zero(float* z) { z[threadIdx.x] = 0.f; }

// ---------- s = w @ affine_w^T + affine_b ----------
__global__ __launch_bounds__(256) void k_affine(const float* __restrict__ w,
                                                const float* __restrict__ aw,
                                                const float* __restrict__ ab,
                                                float* __restrict__ s) {
  int idx = blockIdx.x * 256 + threadIdx.x;       // 16*512
  int n = idx >> 9, c = idx & 511;
  const float4* wr = (const float4*)(w + (size_t)n * WD);
  const float4* ar = (const float4*)(aw + (size_t)c * WD);
  float acc = 0.f;
#pragma unroll 4
  for (int k = 0; k < WD / 4; ++k) {
    float4 a = wr[k], b = ar[k];
    acc += a.x * b.x + a.y * b.y + a.z * b.z + a.w * b.w;
  }
  s[idx] = acc + ab[c];
}

// ---------- d = rsqrt(sum_i s^2 * w2 + 1e-8) ----------
__global__ __launch_bounds__(256) void k_demod(const float* __restrict__ s,
                                               const float* __restrict__ cw,
                                               float* __restrict__ d) {
  __shared__ float w2[CIN];
  int o = blockIdx.x;
  const float* wr = cw + (size_t)o * CIN * 9;
  for (int i = threadIdx.x; i < CIN; i += 256) {
    float acc = 0.f;
#pragma unroll
    for (int t = 0; t < 9; ++t) { float v = wr[i * 9 + t]; acc += v * v; }
    w2[i] = acc;
  }
  __syncthreads();
  int wave = threadIdx.x >> 6, lane = threadIdx.x & 63;
  for (int nn = wave; nn < N_; nn += 4) {
    float acc = 0.f;
    for (int i = lane; i < CIN; i += 64) {
      float sv = s[nn * CIN + i];
      acc += sv * sv * w2[i];
    }
#pragma unroll
    for (int off = 32; off > 0; off >>= 1) acc += __shfl_down(acc, off);
    if (lane == 0) {
      float a = acc + 1e-8f;
      float r = rsqrtf(a);
      r = r * (1.5f - 0.5f * a * r * r);   // Newton refine
      d[nn * COUT + o] = r;
    }
  }
}

// ---------- weights -> bf16, layout [tap][o][i] ----------
__global__ __launch_bounds__(256) void k_wprep(const float* __restrict__ cw,
                                               u16* __restrict__ wbt) {
  int idx = blockIdx.x * 256 + threadIdx.x;
  if (idx >= COUT * CIN * 9) return;
  int t = idx % 9; int oi = idx / 9; int i = oi & 511; int o = oi >> 9;
  wbt[((size_t)t * COUT + o) * CIN + i] = f2bf(cw[idx]);
}

// ---------- x * s -> bf16 NHWC  xb[n][p][c] ----------
__global__ __launch_bounds__(256) void k_xmod(const float* __restrict__ x,
                                              const float* __restrict__ s,
                                              u16* __restrict__ xb) {
  __shared__ float tile[64][65];
  int b = blockIdx.x;                 // 16 * 8 * 64
  int pt = b & 63; int ct = (b >> 6) & 7; int n = b >> 9;
  int c0 = ct * 64, p0 = pt * 64;
  const float* xp = x + ((size_t)n * CIN + c0) * P_ + p0;
  int t = threadIdx.x;
#pragma unroll
  for (int pass = 0; pass < 4; ++pass) {
    int r = pass * 16 + (t >> 4);
    int col4 = (t & 15);
    float4 v = *(const float4*)(xp + (size_t)r * P_ + col4 * 4);
    float sc = s[n * CIN + c0 + r];
    tile[r][col4 * 4 + 0] = v.x * sc;
    tile[r][col4 * 4 + 1] = v.y * sc;
    tile[r][col4 * 4 + 2] = v.z * sc;
    tile[r][col4 * 4 + 3] = v.w * sc;
  }
  __syncthreads();
  int p = t >> 2, cq = (t & 3) * 16;
  union { u16 us[16]; uint4 q[2]; } pk;
#pragma unroll
  for (int j = 0; j < 16; ++j) pk.us[j] = f2bf(tile[cq + j][p]);
  uint4* dst = (uint4*)(xb + ((size_t)n * P_ + p0 + p) * CIN + c0 + cq);
  dst[0] = pk.q[0];
  dst[1] = pk.q[1];
}

// ---------- main conv: implicit GEMM, 256x256 tile, BK=32, ring-4 LDS ----------
// 512 threads = 8 waves (2 wr x 4 wc); per-wave output 128x64.
// m201-style rhythm: per BK=32 tile, 2 phases x {ds_read subtile | stage issue |
// lgkmcnt(0) | prio1 16 MFMA prio0}, separated by s_barrier; gate = counted
// vmcnt(8) (prefetch depth 3 on a ring-4: staged buffer (t+3)&3 was fully
// consumed before gate-t barrier, so no race). vmcnt never drains in main loop.
__global__ __launch_bounds__(512, 1) void k_conv(const u16* __restrict__ xb,
                                                 const u16* __restrict__ wbt,
                                                 const u16* __restrict__ zp,
                                                 const float* __restrict__ dmod,
                                                 const float* __restrict__ cbias,
                                                 const float* __restrict__ noise,
                                                 const float* __restrict__ nstr,
                                                 float* __restrict__ out) {
  __shared__ u16 smA[4][8192];   // [buf][256 rows x 32 ch] 16 KB each
  __shared__ u16 smB[4][8192];

  // bijective XCD swizzle: nwg=512 -> XCD x gets n in {2x,2x+1}
  int bid = blockIdx.x;
  int wg = (bid & 7) * 64 + (bid >> 3);
  int n = wg >> 5;
  int rem = wg & 31;
  int ob = rem >> 4;            // 0..1   (out-ch block of 256)
  int pb = rem & 15;            // 0..15  (spatial block of 256 = 4 rows)

  int tid = threadIdx.x;
  int wv = tid >> 6, l = tid & 63;
  int wr = wv >> 2, wc = wv & 3;
  int lrow = l & 15, kgrp = l >> 4;
  int prs = kgrp ^ ((lrow >> 1) & 3);          // read phys slot (swizzle)

  // staging constants
  int srow = tid >> 2;                          // 0..127 row within group
  int lslot = (tid & 3) ^ ((tid >> 3) & 3);     // logical k-slot staged
  const u16* xbn = xb + (size_t)n * P_ * CIN;
  int hg[2], wgp[2];
#pragma unroll
  for (int g = 0; g < 2; ++g) {
    int ploc = g * 128 + srow;
    hg[g] = pb * 4 + (ploc >> 6);
    wgp[g] = ploc & 63;
  }
  const u16* srcA_base[2];
#pragma unroll
  for (int g = 0; g < 2; ++g)
    srcA_base[g] = wbt + (size_t)(ob * 256 + g * 128 + srow) * CIN + lslot * 8;

  // from-scratch stagers (prologue only)
  auto stage_A = [&](int tt) {
    int b = tt & 3;
    int tapn = tt >> 4, cbn = tt & 15;
#pragma unroll
    for (int g = 0; g < 2; ++g) {
      const u16* src = srcA_base[g] + (size_t)tapn * CC + cbn * 32;
      gl_lds16(src, &smA[b][g * 4096 + wv * 512]);
    }
  };
  auto bsrc_for_tap = [&](int tapn, int g) -> const u16* {
    int dh = tapn < 3 ? -1 : (tapn < 6 ? 0 : 1);
    int dw = tapn - (dh + 1) * 3 - 1;
    int hh = hg[g] + dh, ww = wgp[g] + dw;
    bool val = ((unsigned)hh < 64u) && ((unsigned)ww < 64u);
    return val ? (xbn + ((size_t)((hh << 6) + ww)) * CIN + lslot * 8)
               : (zp + lslot * 8);
  };
  auto stage_B = [&](int tt) {
    int b = tt & 3;
    int tapn = tt >> 4, cbn = tt & 15;
#pragma unroll
    for (int g = 0; g < 2; ++g)
      gl_lds16(bsrc_for_tap(tapn, g) + cbn * 32, &smB[b][g * 4096 + wv * 512]);
  };

  f32x4 acc0[4][4], acc1[4][4];
  f32x4 zero = {0.f, 0.f, 0.f, 0.f};
#pragma unroll
  for (int i = 0; i < 4; ++i)
#pragma unroll
    for (int j = 0; j < 4; ++j) { acc0[i][j] = zero; acc1[i][j] = zero; }

  // prologue: stage tiles 0,1,2 (12 loads in flight; order A,B per tile)
  stage_A(0); stage_B(0);
  stage_A(1); stage_B(1);
  stage_A(2); stage_B(2);

  // rolling source pointers for tile t+3 (init: tile 3 -> tap 0, cb 3)
  int tap3 = 0, cb3 = 3;
  const u16* rpA[2];
  const u16* rpB[2];
#pragma unroll
  for (int g = 0; g < 2; ++g) {
    rpA[g] = srcA_base[g] + 3 * 32;
    rpB[g] = bsrc_for_tap(0, g) + 3 * 32;
  }

  for (int t = 0; t < 144; ++t) {      // 9 taps * 16 cb
    int b = t & 3;
    int bs = (t + 3) & 3;
    // gate: this wave's tile-t loads retired; barrier -> all waves' retired
    if (t <= 141)      asm volatile("s_waitcnt vmcnt(8)" ::: "memory");
    else if (t == 142) asm volatile("s_waitcnt vmcnt(4)" ::: "memory");
    else               asm volatile("s_waitcnt vmcnt(0)" ::: "memory");
    __builtin_amdgcn_s_barrier();
    __builtin_amdgcn_sched_barrier(0);

    const u16* A = smA[b];
    const u16* B = smB[b];

    // ---- phase 0: B frags + A rows 0-63; stage A(t+3); 16 MFMA (acc0) ----
    bf16x8 Af[4], Bf[4];
#pragma unroll
    for (int ni = 0; ni < 4; ++ni)
      Bf[ni] = *(const bf16x8*)&B[(wc * 64 + ni * 16 + lrow) * 32 + prs * 8];
#pragma unroll
    for (int mi = 0; mi < 4; ++mi)
      Af[mi] = *(const bf16x8*)&A[(wr * 128 + mi * 16 + lrow) * 32 + prs * 8];
    if (t <= 140) {
#pragma unroll
      for (int g = 0; g < 2; ++g)
        gl_lds16(rpA[g], &smA[bs][g * 4096 + wv * 512]);
    }
    asm volatile("s_waitcnt lgkmcnt(0)" ::: "memory");
    __builtin_amdgcn_sched_barrier(0);
    __builtin_amdgcn_s_setprio(1);
#pragma unroll
    for (int mi = 0; mi < 4; ++mi)
#pragma unroll
      for (int ni = 0; ni < 4; ++ni)
        acc0[mi][ni] = __builtin_amdgcn_mfma_f32_16x16x32_bf16(
            Af[mi], Bf[ni], acc0[mi][ni], 0, 0, 0);
    __builtin_amdgcn_s_setprio(0);
    __builtin_amdgcn_s_barrier();     // phase boundary

    // ---- phase 1: A rows 64-127; stage B(t+3); 16 MFMA (acc1) ----
#pragma unroll
    for (int mi = 0; mi < 4; ++mi)
      Af[mi] = *(const bf16x8*)&A[(wr * 128 + 64 + mi * 16 + lrow) * 32 + prs * 8];
    if (t <= 140) {
#pragma unroll
      for (int g = 0; g < 2; ++g)
        gl_lds16(rpB[g], &smB[bs][g * 4096 + wv * 512]);
      // advance rolling pointers to tile t+4
      cb3++;
      if (cb3 == 16) {
        cb3 = 0; tap3++;
#pragma unroll
        for (int g = 0; g < 2; ++g) {
          rpA[g] = srcA_base[g] + (size_t)tap3 * CC;
          rpB[g] = bsrc_for_tap(tap3, g);
        }
      } else {
#pragma unroll
        for (int g = 0; g < 2; ++g) { rpA[g] += 32; rpB[g] += 32; }
      }
    }
    asm volatile("s_waitcnt lgkmcnt(0)" ::: "memory");
    __builtin_amdgcn_sched_barrier(0);
    __builtin_amdgcn_s_setprio(1);
#pragma unroll
    for (int mi = 0; mi < 4; ++mi)
#pragma unroll
      for (int ni = 0; ni < 4; ++ni)
        acc1[mi][ni] = __builtin_amdgcn_mfma_f32_16x16x32_bf16(
            Af[mi], Bf[ni], acc1[mi][ni], 0, 0, 0);
    __builtin_amdgcn_s_setprio(0);
  }

  // epilogue: demod scale + bias + noise + LeakyReLU(0.2)
  float ns = nstr[0];
  const float* noise_n = noise + (size_t)n * P_;
  float nz[4];
#pragma unroll
  for (int ni = 0; ni < 4; ++ni)
    nz[ni] = noise_n[pb * 256 + wc * 64 + ni * 16 + lrow] * ns;

  auto epi = [&](f32x4 (&A_)[4][4], int qm) {
#pragma unroll
    for (int mi = 0; mi < 4; ++mi) {
      int o0 = ob * 256 + wr * 128 + qm * 64 + mi * 16 + kgrp * 4;
#pragma unroll
      for (int r = 0; r < 4; ++r) {
        int o = o0 + r;
        float dv = dmod[n * COUT + o];
        float bv = cbias[o];
        float* orow = out + ((size_t)(n * COUT + o)) * P_ + pb * 256 + wc * 64;
#pragma unroll
        for (int ni = 0; ni < 4; ++ni) {
          float v = A_[mi][ni][r] * dv + bv + nz[ni];
          orow[ni * 16 + lrow] = v >= 0.f ? v : 0.2f * v;
        }
      }
    }
  };
  epi(acc0, 0);
  epi(acc1, 1);
}

// ---------- fallback (small ws): direct conv ----------
__global__ __launch_bounds__(64) void k_conv_naive(const float* __restrict__ x,
                                                   const float* __restrict__ cw,
                                                   const float* __restrict__ cbias,
                                                   const float* __restrict__ noise,
                                                   const float* __restrict__ nstr,
                                                   const float* __restrict__ s,
                                                   const float* __restrict__ d,
                                                   float* __restrict__ out) {
  int bid = blockIdx.x;                 // 16*512*64 = (n,o,h)
  int h = bid & 63; int o = (bid >> 6) & 511; int n = bid >> 15;
  int wcol = threadIdx.x;
  float acc = 0.f;
  for (int i = 0; i < CIN; ++i) {
    float sv = s[n * CIN + i];
    const float* xrow = x + ((size_t)(n * CIN + i)) * P_;
    const float* wrp = cw + ((size_t)o * CIN + i) * 9;
#pragma unroll
    for (int t = 0; t < 9; ++t) {
      int hh = h + t / 3 - 1, ww = wcol + t % 3 - 1;
      float xv = ((unsigned)hh < 64u && (unsigned)ww < 64u) ? xrow[hh * 64 + ww] : 0.f;
      acc += xv * sv * wrp[t];
    }
  }
  float v = acc * d[n * COUT + o] + cbias[o] + noise[(size_t)n * P_ + h * 64 + wcol] * nstr[0];
  out[((size_t)(n * COUT + o)) * P_ + h * 64 + wcol] = v >= 0.f ? v : 0.2f * v;
}

extern "C" void kernel_launch(void* const* d_in, const int* in_sizes, int n_in,
                              void* d_out, int out_size, void* d_ws, size_t ws_size,
                              hipStream_t stream) {
  const float* x    = (const float*)d_in[0];
  const float* w    = (const float*)d_in[1];
  const float* noise= (const float*)d_in[2];
  const float* aw   = (const float*)d_in[3];
  const float* ab   = (const float*)d_in[4];
  const float* nstr = (const float*)d_in[5];
  const float* cw   = (const float*)d_in[6];
  const float* cb   = (const float*)d_in[7];
  float* out = (float*)d_out;
  char* ws = (char*)d_ws;
  float* s = (float*)(ws + OFF_S);
  float* d = (float*)(ws + OFF_D);

  k_affine<<<(N_ * COUT) / 256, 256, 0, stream>>>(w, aw, ab, s);
  k_demod<<<COUT, 256, 0, stream>>>(s, cw, d);

  if (ws_size >= WS_NEED) {
    u16* zp  = (u16*)(ws + OFF_Z);
    u16* wbt = (u16*)(ws + OFF_WBT);
    u16* xbb = (u16*)(ws + OFF_XB);
    k_zero<<<1, 256, 0, stream>>>((float*)zp);
    k_wprep<<<(COUT * CIN * 9 + 255) / 256, 256, 0, stream>>>(cw, wbt);
    k_xmod<<<N_ * 8 * 64, 256, 0, stream>>>(x, s, xbb);
    k_conv<<<512, 512, 0, stream>>>(xbb, wbt, zp, d, cb, noise, nstr, out);
  } else {
    k_conv_naive<<<N_ * COUT * 64, 64, 0, stream>>>(x, cw, cb, noise, nstr, s, d, out);
  }
}

// Round 4
// 340.702 us; speedup vs baseline: 1.3256x; 1.0065x over previous
//
#include <hip/hip_runtime.h>
#include <hip/hip_bf16.h>

typedef unsigned short u16;
typedef short bf16x8 __attribute__((ext_vector_type(8)));
typedef float f32x4 __attribute__((ext_vector_type(4)));

#define N_    16
#define CIN   512
#define COUT  512
#define WD    512
#define P_    4096   // 64*64 spatial
#define CC    (COUT * CIN)

// ws layout (bytes)
#define OFF_S   0u
#define OFF_D   32768u
#define OFF_Z   65536u          // 1 KB zero page
#define OFF_WBT 131072u         // 9*512*512*2 = 4718592 B
#define OFF_XB  8388608u        // 16*4096*512*2 = 67108864 B
#define WS_NEED (OFF_XB + 67108864u)

__device__ __forceinline__ u16 f2bf(float f) {
  union { float f; unsigned u; } a; a.f = f;
  unsigned r = a.u + 0x7fffu + ((a.u >> 16) & 1u);   // RNE
  return (u16)(r >> 16);
}

__device__ __forceinline__ void gl_lds16(const u16* g, u16* l) {
  __builtin_amdgcn_global_load_lds(
      (const __attribute__((address_space(1))) void*)g,
      (__attribute__((address_space(3))) void*)l, 16, 0, 0);
}

// ---------- zero page ----------
__global__ void k_zero(float* z) { z[threadIdx.x] = 0.f; }

// ---------- s = w @ affine_w^T + affine_b ----------
__global__ __launch_bounds__(256) void k_affine(const float* __restrict__ w,
                                                const float* __restrict__ aw,
                                                const float* __restrict__ ab,
                                                float* __restrict__ s) {
  int idx = blockIdx.x * 256 + threadIdx.x;       // 16*512
  int n = idx >> 9, c = idx & 511;
  const float4* wr = (const float4*)(w + (size_t)n * WD);
  const float4* ar = (const float4*)(aw + (size_t)c * WD);
  float acc = 0.f;
#pragma unroll 4
  for (int k = 0; k < WD / 4; ++k) {
    float4 a = wr[k], b = ar[k];
    acc += a.x * b.x + a.y * b.y + a.z * b.z + a.w * b.w;
  }
  s[idx] = acc + ab[c];
}

// ---------- d = rsqrt(sum_i s^2 * w2 + 1e-8) ----------
__global__ __launch_bounds__(256) void k_demod(const float* __restrict__ s,
                                               const float* __restrict__ cw,
                                               float* __restrict__ d) {
  __shared__ float w2[CIN];
  int o = blockIdx.x;
  const float* wr = cw + (size_t)o * CIN * 9;
  for (int i = threadIdx.x; i < CIN; i += 256) {
    float acc = 0.f;
#pragma unroll
    for (int t = 0; t < 9; ++t) { float v = wr[i * 9 + t]; acc += v * v; }
    w2[i] = acc;
  }
  __syncthreads();
  int wave = threadIdx.x >> 6, lane = threadIdx.x & 63;
  for (int nn = wave; nn < N_; nn += 4) {
    float acc = 0.f;
    for (int i = lane; i < CIN; i += 64) {
      float sv = s[nn * CIN + i];
      acc += sv * sv * w2[i];
    }
#pragma unroll
    for (int off = 32; off > 0; off >>= 1) acc += __shfl_down(acc, off);
    if (lane == 0) {
      float a = acc + 1e-8f;
      float r = rsqrtf(a);
      r = r * (1.5f - 0.5f * a * r * r);   // Newton refine
      d[nn * COUT + o] = r;
    }
  }
}

// ---------- weights -> bf16, layout [tap][o][i] ----------
__global__ __launch_bounds__(256) void k_wprep(const float* __restrict__ cw,
                                               u16* __restrict__ wbt) {
  int idx = blockIdx.x * 256 + threadIdx.x;
  if (idx >= COUT * CIN * 9) return;
  int t = idx % 9; int oi = idx / 9; int i = oi & 511; int o = oi >> 9;
  wbt[((size_t)t * COUT + o) * CIN + i] = f2bf(cw[idx]);
}

// ---------- x * s -> bf16 NHWC  xb[n][p][c] ----------
__global__ __launch_bounds__(256) void k_xmod(const float* __restrict__ x,
                                              const float* __restrict__ s,
                                              u16* __restrict__ xb) {
  __shared__ float tile[64][65];
  int b = blockIdx.x;                 // 16 * 8 * 64
  int pt = b & 63; int ct = (b >> 6) & 7; int n = b >> 9;
  int c0 = ct * 64, p0 = pt * 64;
  const float* xp = x + ((size_t)n * CIN + c0) * P_ + p0;
  int t = threadIdx.x;
#pragma unroll
  for (int pass = 0; pass < 4; ++pass) {
    int r = pass * 16 + (t >> 4);
    int col4 = (t & 15);
    float4 v = *(const float4*)(xp + (size_t)r * P_ + col4 * 4);
    float sc = s[n * CIN + c0 + r];
    tile[r][col4 * 4 + 0] = v.x * sc;
    tile[r][col4 * 4 + 1] = v.y * sc;
    tile[r][col4 * 4 + 2] = v.z * sc;
    tile[r][col4 * 4 + 3] = v.w * sc;
  }
  __syncthreads();
  int p = t >> 2, cq = (t & 3) * 16;
  union { u16 us[16]; uint4 q[2]; } pk;
#pragma unroll
  for (int j = 0; j < 16; ++j) pk.us[j] = f2bf(tile[cq + j][p]);
  uint4* dst = (uint4*)(xb + ((size_t)n * P_ + p0 + p) * CIN + c0 + cq);
  dst[0] = pk.q[0];
  dst[1] = pk.q[1];
}

// ---------- main conv: implicit GEMM, 256x256 tile, BK=32, ring-4 LDS ----------
// 512 threads = 8 waves (2 wr x 4 wc); per-wave output 128x64.
// Pipelined tile body (1 barrier / 32 MFMA): gate {vmcnt(8); s_barrier};
// issue ALL 12 ds_reads (Bf+Af0 first, then Af1 — order pinned); issue 4
// gl_lds stage(t+3); lgkmcnt(4) -> 16 MFMA acc0 (Af1 reads land underneath);
// lgkmcnt(0) -> 16 MFMA acc1. vmcnt never drains in main loop.
__global__ __launch_bounds__(512, 1) void k_conv(const u16* __restrict__ xb,
                                                 const u16* __restrict__ wbt,
                                                 const u16* __restrict__ zp,
                                                 const float* __restrict__ dmod,
                                                 const float* __restrict__ cbias,
                                                 const float* __restrict__ noise,
                                                 const float* __restrict__ nstr,
                                                 float* __restrict__ out) {
  __shared__ u16 smA[4][8192];   // [buf][256 rows x 32 ch] 16 KB each
  __shared__ u16 smB[4][8192];

  // bijective XCD swizzle: nwg=512 -> XCD x gets n in {2x,2x+1}
  int bid = blockIdx.x;
  int wg = (bid & 7) * 64 + (bid >> 3);
  int n = wg >> 5;
  int rem = wg & 31;
  int ob = rem >> 4;            // 0..1   (out-ch block of 256)
  int pb = rem & 15;            // 0..15  (spatial block of 256 = 4 rows)

  int tid = threadIdx.x;
  int wv = tid >> 6, l = tid & 63;
  int wr = wv >> 2, wc = wv & 3;
  int lrow = l & 15, kgrp = l >> 4;
  int prs = kgrp ^ ((lrow >> 1) & 3);          // read phys slot (swizzle)

  // staging constants
  int srow = tid >> 2;                          // 0..127 row within group
  int lslot = (tid & 3) ^ ((tid >> 3) & 3);     // logical k-slot staged
  const u16* xbn = xb + (size_t)n * P_ * CIN;
  int hg[2], wgp[2];
#pragma unroll
  for (int g = 0; g < 2; ++g) {
    int ploc = g * 128 + srow;
    hg[g] = pb * 4 + (ploc >> 6);
    wgp[g] = ploc & 63;
  }
  const u16* srcA_base[2];
#pragma unroll
  for (int g = 0; g < 2; ++g)
    srcA_base[g] = wbt + (size_t)(ob * 256 + g * 128 + srow) * CIN + lslot * 8;

  // from-scratch stagers (prologue only)
  auto stage_A = [&](int tt) {
    int b = tt & 3;
    int tapn = tt >> 4, cbn = tt & 15;
#pragma unroll
    for (int g = 0; g < 2; ++g) {
      const u16* src = srcA_base[g] + (size_t)tapn * CC + cbn * 32;
      gl_lds16(src, &smA[b][g * 4096 + wv * 512]);
    }
  };
  auto bsrc_for_tap = [&](int tapn, int g) -> const u16* {
    int dh = tapn < 3 ? -1 : (tapn < 6 ? 0 : 1);
    int dw = tapn - (dh + 1) * 3 - 1;
    int hh = hg[g] + dh, ww = wgp[g] + dw;
    bool val = ((unsigned)hh < 64u) && ((unsigned)ww < 64u);
    return val ? (xbn + ((size_t)((hh << 6) + ww)) * CIN + lslot * 8)
               : (zp + lslot * 8);
  };
  auto stage_B = [&](int tt) {
    int b = tt & 3;
    int tapn = tt >> 4, cbn = tt & 15;
#pragma unroll
    for (int g = 0; g < 2; ++g)
      gl_lds16(bsrc_for_tap(tapn, g) + cbn * 32, &smB[b][g * 4096 + wv * 512]);
  };

  f32x4 acc0[4][4], acc1[4][4];
  f32x4 zero = {0.f, 0.f, 0.f, 0.f};
#pragma unroll
  for (int i = 0; i < 4; ++i)
#pragma unroll
    for (int j = 0; j < 4; ++j) { acc0[i][j] = zero; acc1[i][j] = zero; }

  // prologue: stage tiles 0,1,2 (12 loads in flight; 4 per tile: A then B)
  stage_A(0); stage_B(0);
  stage_A(1); stage_B(1);
  stage_A(2); stage_B(2);

  // rolling source pointers for tile t+3 (init: tile 3 -> tap 0, cb 3)
  int tap3 = 0, cb3 = 3;
  const u16* rpA[2];
  const u16* rpB[2];
#pragma unroll
  for (int g = 0; g < 2; ++g) {
    rpA[g] = srcA_base[g] + 3 * 32;
    rpB[g] = bsrc_for_tap(0, g) + 3 * 32;
  }

  for (int t = 0; t < 144; ++t) {      // 9 taps * 16 cb
    int b = t & 3;
    int bs = (t + 3) & 3;
    // gate: tile-t loads retired everywhere after barrier
    if (t <= 141)      asm volatile("s_waitcnt vmcnt(8)" ::: "memory");
    else if (t == 142) asm volatile("s_waitcnt vmcnt(4)" ::: "memory");
    else               asm volatile("s_waitcnt vmcnt(0)" ::: "memory");
    __builtin_amdgcn_s_barrier();
    __builtin_amdgcn_sched_barrier(0);

    const u16* A = smA[b];
    const u16* B = smB[b];

    // ---- issue all 12 fragment reads; order pinned: Bf,Af0 | Af1 ----
    bf16x8 Bf[4], Af0[4], Af1[4];
#pragma unroll
    for (int ni = 0; ni < 4; ++ni)
      Bf[ni] = *(const bf16x8*)&B[(wc * 64 + ni * 16 + lrow) * 32 + prs * 8];
#pragma unroll
    for (int mi = 0; mi < 4; ++mi)
      Af0[mi] = *(const bf16x8*)&A[(wr * 128 + mi * 16 + lrow) * 32 + prs * 8];
    __builtin_amdgcn_sched_barrier(0);
#pragma unroll
    for (int mi = 0; mi < 4; ++mi)
      Af1[mi] = *(const bf16x8*)&A[(wr * 128 + 64 + mi * 16 + lrow) * 32 + prs * 8];

    // ---- stage tile t+3 (vmcnt ops only) + pointer advance ----
    if (t <= 140) {
#pragma unroll
      for (int g = 0; g < 2; ++g)
        gl_lds16(rpA[g], &smA[bs][g * 4096 + wv * 512]);
#pragma unroll
      for (int g = 0; g < 2; ++g)
        gl_lds16(rpB[g], &smB[bs][g * 4096 + wv * 512]);
      cb3++;
      if (cb3 == 16) {
        cb3 = 0; tap3++;
#pragma unroll
        for (int g = 0; g < 2; ++g) {
          rpA[g] = srcA_base[g] + (size_t)tap3 * CC;
          rpB[g] = bsrc_for_tap(tap3, g);
        }
      } else {
#pragma unroll
        for (int g = 0; g < 2; ++g) { rpA[g] += 32; rpB[g] += 32; }
      }
    }

    // ---- wait for Bf+Af0 only (Af1 still in flight under acc0 MFMAs) ----
    asm volatile("s_waitcnt lgkmcnt(4)" ::: "memory");
    __builtin_amdgcn_sched_barrier(0);
    __builtin_amdgcn_s_setprio(1);
#pragma unroll
    for (int mi = 0; mi < 4; ++mi)
#pragma unroll
      for (int ni = 0; ni < 4; ++ni)
        acc0[mi][ni] = __builtin_amdgcn_mfma_f32_16x16x32_bf16(
            Af0[mi], Bf[ni], acc0[mi][ni], 0, 0, 0);
    __builtin_amdgcn_s_setprio(0);

    asm volatile("s_waitcnt lgkmcnt(0)" ::: "memory");
    __builtin_amdgcn_sched_barrier(0);
    __builtin_amdgcn_s_setprio(1);
#pragma unroll
    for (int mi = 0; mi < 4; ++mi)
#pragma unroll
      for (int ni = 0; ni < 4; ++ni)
        acc1[mi][ni] = __builtin_amdgcn_mfma_f32_16x16x32_bf16(
            Af1[mi], Bf[ni], acc1[mi][ni], 0, 0, 0);
    __builtin_amdgcn_s_setprio(0);
  }

  // epilogue: demod scale + bias + noise + LeakyReLU(0.2)
  float ns = nstr[0];
  const float* noise_n = noise + (size_t)n * P_;
  float nz[4];
#pragma unroll
  for (int ni = 0; ni < 4; ++ni)
    nz[ni] = noise_n[pb * 256 + wc * 64 + ni * 16 + lrow] * ns;

  auto epi = [&](f32x4 (&A_)[4][4], int qm) {
#pragma unroll
    for (int mi = 0; mi < 4; ++mi) {
      int o0 = ob * 256 + wr * 128 + qm * 64 + mi * 16 + kgrp * 4;
#pragma unroll
      for (int r = 0; r < 4; ++r) {
        int o = o0 + r;
        float dv = dmod[n * COUT + o];
        float bv = cbias[o];
        float* orow = out + ((size_t)(n * COUT + o)) * P_ + pb * 256 + wc * 64;
#pragma unroll
        for (int ni = 0; ni < 4; ++ni) {
          float v = A_[mi][ni][r] * dv + bv + nz[ni];
          orow[ni * 16 + lrow] = v >= 0.f ? v : 0.2f * v;
        }
      }
    }
  };
  epi(acc0, 0);
  epi(acc1, 1);
}

// ---------- fallback (small ws): direct conv ----------
__global__ __launch_bounds__(64) void k_conv_naive(const float* __restrict__ x,
                                                   const float* __restrict__ cw,
                                                   const float* __restrict__ cbias,
                                                   const float* __restrict__ noise,
                                                   const float* __restrict__ nstr,
                                                   const float* __restrict__ s,
                                                   const float* __restrict__ d,
                                                   float* __restrict__ out) {
  int bid = blockIdx.x;                 // 16*512*64 = (n,o,h)
  int h = bid & 63; int o = (bid >> 6) & 511; int n = bid >> 15;
  int wcol = threadIdx.x;
  float acc = 0.f;
  for (int i = 0; i < CIN; ++i) {
    float sv = s[n * CIN + i];
    const float* xrow = x + ((size_t)(n * CIN + i)) * P_;
    const float* wrp = cw + ((size_t)o * CIN + i) * 9;
#pragma unroll
    for (int t = 0; t < 9; ++t) {
      int hh = h + t / 3 - 1, ww = wcol + t % 3 - 1;
      float xv = ((unsigned)hh < 64u && (unsigned)ww < 64u) ? xrow[hh * 64 + ww] : 0.f;
      acc += xv * sv * wrp[t];
    }
  }
  float v = acc * d[n * COUT + o] + cbias[o] + noise[(size_t)n * P_ + h * 64 + wcol] * nstr[0];
  out[((size_t)(n * COUT + o)) * P_ + h * 64 + wcol] = v >= 0.f ? v : 0.2f * v;
}

extern "C" void kernel_launch(void* const* d_in, const int* in_sizes, int n_in,
                              void* d_out, int out_size, void* d_ws, size_t ws_size,
                              hipStream_t stream) {
  const float* x    = (const float*)d_in[0];
  const float* w    = (const float*)d_in[1];
  const float* noise= (const float*)d_in[2];
  const float* aw   = (const float*)d_in[3];
  const float* ab   = (const float*)d_in[4];
  const float* nstr = (const float*)d_in[5];
  const float* cw   = (const float*)d_in[6];
  const float* cb   = (const float*)d_in[7];
  float* out = (float*)d_out;
  char* ws = (char*)d_ws;
  float* s = (float*)(ws + OFF_S);
  float* d = (float*)(ws + OFF_D);

  k_affine<<<(N_ * COUT) / 256, 256, 0, stream>>>(w, aw, ab, s);
  k_demod<<<COUT, 256, 0, stream>>>(s, cw, d);

  if (ws_size >= WS_NEED) {
    u16* zp  = (u16*)(ws + OFF_Z);
    u16* wbt = (u16*)(ws + OFF_WBT);
    u16* xbb = (u16*)(ws + OFF_XB);
    k_zero<<<1, 256, 0, stream>>>((float*)zp);
    k_wprep<<<(COUT * CIN * 9 + 255) / 256, 256, 0, stream>>>(cw, wbt);
    k_xmod<<<N_ * 8 * 64, 256, 0, stream>>>(x, s, xbb);
    k_conv<<<512, 512, 0, stream>>>(xbb, wbt, zp, d, cb, noise, nstr, out);
  } else {
    k_conv_naive<<<N_ * COUT * 64, 64, 0, stream>>>(x, cw, cb, noise, nstr, s, d, out);
  }
}